// Round 1
// baseline (625.400 us; speedup 1.0000x reference)
//
#include <hip/hip_runtime.h>

// Workspace layout (bytes). Total ~30.4 MB.
#define WS_CNT      0u
#define WS_ROWSTART 400128u
#define WS_CURSOR   800256u
#define WS_DINV     1200384u
#define WS_BSUM     1600512u
#define WS_BOFF     1602560u
#define WS_FLAG     1604608u
#define WS_G        1604864u
#define WS_CSR      (WS_G + 16000000u)

// Detect whether edge_index arrived as int64 (odd int32 words all zero) or int32.
static __global__ void k_detect(const int* __restrict__ ei, int* __restrict__ flag) {
    if (blockIdx.x == 0 && threadIdx.x == 0) {
        int allz = 1;
        for (int t = 1; t < 256; t += 2) {
            if (ei[t] != 0) { allz = 0; break; }
        }
        *flag = allz;
    }
}

// cnt[dst] += 1 for every edge (int atomics).
static __global__ void k_deg(const int* __restrict__ ei, int E,
                             const int* __restrict__ flag, int* __restrict__ cnt) {
    const int is64 = *flag;
    int e = blockIdx.x * blockDim.x + threadIdx.x;
    const int stride = gridDim.x * blockDim.x;
    if (is64) {
        for (; e < E; e += stride) atomicAdd(&cnt[ei[2 * (E + e)]], 1);
    } else {
        for (; e < E; e += stride) atomicAdd(&cnt[ei[E + e]], 1);
    }
}

// Per-block sums of cnt.
static __global__ void k_scanA(const int* __restrict__ cnt, int n, int* __restrict__ bsum) {
    __shared__ int lds[256];
    const int i = blockIdx.x * 256 + threadIdx.x;
    lds[threadIdx.x] = (i < n) ? cnt[i] : 0;
    __syncthreads();
    for (int s = 128; s > 0; s >>= 1) {
        if ((int)threadIdx.x < s) lds[threadIdx.x] += lds[threadIdx.x + s];
        __syncthreads();
    }
    if (threadIdx.x == 0) bsum[blockIdx.x] = lds[0];
}

// Exclusive scan of block sums (nb <= 512), single block of 512 threads.
static __global__ void k_scanB(const int* __restrict__ bsum, int nb, int* __restrict__ boff) {
    __shared__ int lds[512];
    const int t = threadIdx.x;
    const int v = (t < nb) ? bsum[t] : 0;
    lds[t] = v;
    __syncthreads();
    for (int s = 1; s < 512; s <<= 1) {
        int add = (t >= s) ? lds[t - s] : 0;
        __syncthreads();
        lds[t] += add;
        __syncthreads();
    }
    if (t < nb) boff[t] = lds[t] - v;  // exclusive
}

// rowstart = global exclusive scan; cursor = copy for the fill kernel.
static __global__ void k_scanC(const int* __restrict__ cnt, int n, const int* __restrict__ boff,
                               int* __restrict__ rowstart, int* __restrict__ cursor) {
    __shared__ int lds[256];
    const int t = threadIdx.x;
    const int i = blockIdx.x * 256 + t;
    const int v = (i < n) ? cnt[i] : 0;
    lds[t] = v;
    __syncthreads();
    for (int s = 1; s < 256; s <<= 1) {
        int add = (t >= s) ? lds[t - s] : 0;
        __syncthreads();
        lds[t] += add;
        __syncthreads();
    }
    if (i < n) {
        const int ex = boff[blockIdx.x] + lds[t] - v;
        rowstart[i] = ex;
        cursor[i]   = ex;
    }
}

static __global__ void k_dinv(const int* __restrict__ cnt, int n, float* __restrict__ dinv) {
    const int i = blockIdx.x * blockDim.x + threadIdx.x;
    if (i < n) dinv[i] = rsqrtf((float)(cnt[i] + 1));  // +1 self-loop; always > 0
}

// Scatter edges into CSR slots (int-atomic cursor).
static __global__ void k_fill(const int* __restrict__ ei, int E,
                              const int* __restrict__ flag,
                              int* __restrict__ cursor, int* __restrict__ csr) {
    const int is64 = *flag;
    int e = blockIdx.x * blockDim.x + threadIdx.x;
    const int stride = gridDim.x * blockDim.x;
    if (is64) {
        for (; e < E; e += stride) {
            const int s = ei[2 * e];
            const int d = ei[2 * (E + e)];
            const int pos = atomicAdd(&cursor[d], 1);
            csr[pos] = s;
        }
    } else {
        for (; e < E; e += stride) {
            const int s = ei[e];
            const int d = ei[E + e];
            const int pos = atomicAdd(&cursor[d], 1);
            csr[pos] = s;
        }
    }
}

// g[i][c] = (x[i,:] @ W[:,c]) * dinv[i].  Thread-per-row, 40 f32 accumulators.
// W indices are wave-uniform -> scalar loads; inner loop is v_fmac with SGPR operand.
static __global__ __launch_bounds__(256) void k_h(const float* __restrict__ x,
                                                  const float* __restrict__ W,
                                                  const float* __restrict__ dinv,
                                                  float* __restrict__ g, int n) {
    const int row = blockIdx.x * 256 + threadIdx.x;
    if (row >= n) return;
    float acc[40];
#pragma unroll
    for (int c = 0; c < 40; ++c) acc[c] = 0.f;
    const float* xr = x + (size_t)row * 512;
    for (int k = 0; k < 512; k += 4) {
        const float4 xv = *reinterpret_cast<const float4*>(xr + k);
        const float xs[4] = {xv.x, xv.y, xv.z, xv.w};
#pragma unroll
        for (int j = 0; j < 4; ++j) {
            const float* wr = W + (size_t)(k + j) * 40;
#pragma unroll
            for (int c = 0; c < 40; ++c) acc[c] = fmaf(xs[j], wr[c], acc[c]);
        }
    }
    const float dv = dinv[row];
    float* gr = g + (size_t)row * 40;
#pragma unroll
    for (int c = 0; c < 40; c += 4) {
        float4 o;
        o.x = acc[c + 0] * dv;
        o.y = acc[c + 1] * dv;
        o.z = acc[c + 2] * dv;
        o.w = acc[c + 3] * dv;
        *reinterpret_cast<float4*>(gr + c) = o;
    }
}

// out[i][c] = dinv[i] * (g[i][c] + sum_{e: dst=i} g[csr[e]][c]) + b[c]
// Thread = (node, class); 6 nodes per 256-thread block (threads 240..255 idle).
static __global__ __launch_bounds__(256) void k_gather(const float* __restrict__ g,
                                                       const int* __restrict__ csr,
                                                       const int* __restrict__ rowstart,
                                                       const int* __restrict__ cnt,
                                                       const float* __restrict__ dinv,
                                                       const float* __restrict__ b,
                                                       float* __restrict__ out, int n) {
    const int t = threadIdx.x;
    if (t >= 240) return;
    const int local = t / 40;
    const int c = t - local * 40;
    const int i = blockIdx.x * 6 + local;
    if (i >= n) return;

    float acc = g[(size_t)i * 40 + c];  // self-loop term (g already has dinv[i] folded in)
    const int s0 = rowstart[i];
    const int e1 = s0 + cnt[i];
    int p = s0;
    for (; p + 4 <= e1; p += 4) {
        const int sa = csr[p + 0];
        const int sb = csr[p + 1];
        const int sc = csr[p + 2];
        const int sd = csr[p + 3];
        float va = g[(size_t)sa * 40 + c];
        float vb = g[(size_t)sb * 40 + c];
        float vc = g[(size_t)sc * 40 + c];
        float vd = g[(size_t)sd * 40 + c];
        acc += va; acc += vb; acc += vc; acc += vd;
    }
    for (; p < e1; ++p) acc += g[(size_t)csr[p] * 40 + c];

    out[(size_t)i * 40 + c] = acc * dinv[i] + b[c];
}

// In-place log_softmax over rows of 40.
static __global__ void k_lsm(float* __restrict__ out, int n) {
    const int i = blockIdx.x * blockDim.x + threadIdx.x;
    if (i >= n) return;
    float* r = out + (size_t)i * 40;
    float v[40];
#pragma unroll
    for (int c = 0; c < 40; c += 4) {
        const float4 t4 = *reinterpret_cast<const float4*>(r + c);
        v[c] = t4.x; v[c + 1] = t4.y; v[c + 2] = t4.z; v[c + 3] = t4.w;
    }
    float m = v[0];
#pragma unroll
    for (int c = 1; c < 40; ++c) m = fmaxf(m, v[c]);
    float s = 0.f;
#pragma unroll
    for (int c = 0; c < 40; ++c) s += __expf(v[c] - m);
    const float l = m + __logf(s);
#pragma unroll
    for (int c = 0; c < 40; c += 4) {
        float4 o;
        o.x = v[c + 0] - l;
        o.y = v[c + 1] - l;
        o.z = v[c + 2] - l;
        o.w = v[c + 3] - l;
        *reinterpret_cast<float4*>(r + c) = o;
    }
}

extern "C" void kernel_launch(void* const* d_in, const int* in_sizes, int n_in,
                              void* d_out, int out_size, void* d_ws, size_t ws_size,
                              hipStream_t stream) {
    const float* x  = (const float*)d_in[0];
    const int*   ei = (const int*)d_in[1];
    const float* W  = (const float*)d_in[2];
    const float* b  = (const float*)d_in[3];
    float* out = (float*)d_out;

    const int N = in_sizes[0] / 512;  // 100000
    const int E = in_sizes[1] / 2;    // 3200000

    char* ws = (char*)d_ws;
    int*   cnt      = (int*)(ws + WS_CNT);
    int*   rowstart = (int*)(ws + WS_ROWSTART);
    int*   cursor   = (int*)(ws + WS_CURSOR);
    float* dinv     = (float*)(ws + WS_DINV);
    int*   bsum     = (int*)(ws + WS_BSUM);
    int*   boff     = (int*)(ws + WS_BOFF);
    int*   flag     = (int*)(ws + WS_FLAG);
    float* g        = (float*)(ws + WS_G);
    int*   csr      = (int*)(ws + WS_CSR);

    const int NB = (N + 255) / 256;  // 391

    hipMemsetAsync(cnt, 0, (size_t)N * sizeof(int), stream);
    k_detect<<<1, 64, 0, stream>>>(ei, flag);
    k_deg<<<2048, 256, 0, stream>>>(ei, E, flag, cnt);
    k_scanA<<<NB, 256, 0, stream>>>(cnt, N, bsum);
    k_scanB<<<1, 512, 0, stream>>>(bsum, NB, boff);
    k_scanC<<<NB, 256, 0, stream>>>(cnt, N, boff, rowstart, cursor);
    k_dinv<<<NB, 256, 0, stream>>>(cnt, N, dinv);
    k_fill<<<2048, 256, 0, stream>>>(ei, E, flag, cursor, csr);
    k_h<<<NB, 256, 0, stream>>>(x, W, dinv, g, N);
    k_gather<<<(N + 5) / 6, 256, 0, stream>>>(g, csr, rowstart, cnt, dinv, b, out, N);
    k_lsm<<<NB, 256, 0, stream>>>(out, N);
}